// Round 6
// baseline (9446.318 us; speedup 1.0000x reference)
//
#include <hip/hip_runtime.h>
#include <math.h>

// PGJANET persistent kernel, round 6.
// 16 batch-groups x 32 col-slice WGs of 256 thr (NS=8 cols). LDS 76.5KB ->
// 2 WGs/CU; co-resident WGs are from DIFFERENT groups (g = wg>>5, pairs
// wg/wg+256 -> g/g+8), so one group's poll-wait is covered by the other
// group's compute. Exchange = self-validating 16B chunks {f0,f1,seq,0} via
// sc0 sc1 dwordx4 (transaction-atomic), producer 128B-contiguous stores,
// consumer 64B quad polls. No flags, no drains, no cache maintenance.

#define B_   128
#define T_   1024
#define H_   256
#define GB   16
#define GC   32
#define MB   8
#define NS   8
#define NTHR 256
#define HPAD 264

typedef float    f32x4 __attribute__((ext_vector_type(4)));
typedef unsigned u32x4 __attribute__((ext_vector_type(4)));

__device__ __forceinline__ void sys_st_x4(unsigned* p, u32x4 v) {
  asm volatile("global_store_dwordx4 %0, %1, off sc0 sc1" :: "v"(p), "v"(v) : "memory");
}
__device__ __forceinline__ void sys_ld_quad(const unsigned* p, u32x4& a, u32x4& b,
                                            u32x4& c, u32x4& d) {
  asm volatile("global_load_dwordx4 %0, %4, off sc0 sc1\n\t"
               "global_load_dwordx4 %1, %4, off offset:16 sc0 sc1\n\t"
               "global_load_dwordx4 %2, %4, off offset:32 sc0 sc1\n\t"
               "global_load_dwordx4 %3, %4, off offset:48 sc0 sc1\n\t"
               "s_waitcnt vmcnt(0)"
               : "=&v"(a), "=&v"(b), "=&v"(c), "=&v"(d) : "v"(p) : "memory");
}

__device__ __forceinline__ float ftanh(float x) {
  x = fminf(fmaxf(x, -15.f), 15.f);
  float e = __expf(-2.f * x);
  return (1.f - e) * __builtin_amdgcn_rcpf(1.f + e);
}
__device__ __forceinline__ float fsigm(float x) {
  x = fminf(fmaxf(x, -30.f), 30.f);
  return __builtin_amdgcn_rcpf(1.f + __expf(-x));
}

__launch_bounds__(NTHR, 2)
__global__ void pgjanet_persist(
    const float* __restrict__ x,   const float* __restrict__ h0,
    const float* __restrict__ Wa,  const float* __restrict__ ba,
    const float* __restrict__ Wp1, const float* __restrict__ bp1,
    const float* __restrict__ Wp2, const float* __restrict__ bp2,
    const float* __restrict__ Wz,  const float* __restrict__ bz,
    const float* __restrict__ Wh,  const float* __restrict__ bh,
    const float* __restrict__ Wo,  const float* __restrict__ bo,
    float* __restrict__ out,        // [B*T*2] then h_n [B*H]
    unsigned* __restrict__ u_ex,    // [GB][1024 chunks * 4 uints]
    unsigned* __restrict__ h_ex)    // [GB][1024 chunks * 4 uints]
{
  __shared__ __align__(16) float w1t[3 * NS * 256];   // 24 KB
  __shared__ __align__(16) float w2t[2 * NS * 512];   // 32 KB
  __shared__ __align__(16) float h_lds[MB * HPAD];    // 8.25 KB
  __shared__ __align__(16) float u_lds[MB * HPAD];    // 8.25 KB
  __shared__ __align__(16) float wo_s[H_ * 2];        // 2 KB
  __shared__ __align__(16) float xin[2 * MB * 4];     // 256 B

  const int wg   = blockIdx.x;
  const int g    = wg >> 5;        // group: co-resident pair wg/wg+256 -> g/g+8
  const int gc   = wg & (GC - 1);
  const int tid  = threadIdx.x;
  const int lane = tid & 63;
  const int wave = tid >> 6;       // 0..3, owns cols {2w, 2w+1} of the WG's 8
  const int mb   = lane >> 3;      // batch 0..7
  const int ks   = lane & 7;       // k-chunk lane (8-way, 4 floats each)
  const int b0   = g * MB;
  const int n0   = gc * NS + wave * 2;

  // ---- one-time weight staging (transposed to [col][k]) ----
  for (int i = tid; i < 3 * NS * 256; i += NTHR) {
    int c = i >> 8, k = i & 255;
    int mat = c >> 3, n = c & 7;
    const float* W = (mat == 0) ? Wa : (mat == 1 ? Wp1 : Wp2);
    w1t[i] = W[(1 + k) * H_ + gc * NS + n];
  }
  for (int i = tid; i < 2 * NS * 512; i += NTHR) {
    int c = i >> 9, k = i & 511;
    int mat = c >> 3, n = c & 7;
    const float* W = (mat == 0) ? Wz : Wh;
    w2t[i] = W[k * H_ + gc * NS + n];
  }
  for (int i = tid; i < H_ * 2; i += NTHR) wo_s[i] = Wo[i];

  float w1r0_[6], b1_[6];
#pragma unroll
  for (int m = 0; m < 3; ++m) {
    const float* W  = (m == 0) ? Wa : (m == 1 ? Wp1 : Wp2);
    const float* bb = (m == 0) ? ba : (m == 1 ? bp1 : bp2);
#pragma unroll
    for (int cc = 0; cc < 2; ++cc) {
      w1r0_[m * 2 + cc] = W[n0 + cc];
      b1_[m * 2 + cc]   = bb[n0 + cc];
    }
  }
  float bz_[2] = { bz[n0], bz[n0 + 1] };
  float bh_[2] = { bh[n0], bh[n0 + 1] };
  const float bo0 = bo[0], bo1 = bo[1];

  // h0 -> h_lds (8 floats per thread) ; x(0) -> xin[0]
  {
    int mbb = tid >> 5, kk = (tid & 31) * 8;
    *(f32x4*)(h_lds + mbb * HPAD + kk)     = *(const f32x4*)(h0 + (b0 + mbb) * H_ + kk);
    *(f32x4*)(h_lds + mbb * HPAD + kk + 4) = *(const f32x4*)(h0 + (b0 + mbb) * H_ + kk + 4);
  }
  if (tid < MB) {
    float2 xt = *(const float2*)(x + ((b0 + tid) * T_) * 2);
    f32x4 xi; xi[0] = xt.x; xi[1] = cosf(xt.y); xi[2] = sinf(xt.y); xi[3] = 0.f;
    *(f32x4*)(xin + tid * 4) = xi;
  }
  __syncthreads();

  unsigned* u_exg = u_ex + g * 4096;           // 1024 chunks * 4 uints
  unsigned* h_exg = h_ex + g * 4096;
  unsigned* u_my  = u_exg + ((gc * 4 + wave) * 8) * 4;   // + mb*4 at store
  unsigned* h_my  = h_exg + ((gc * 4 + wave) * 8) * 4;
  const unsigned* pu = u_exg + tid * 16;       // consumer quad (4 chunks, 64B)
  const unsigned* ph = h_exg + tid * 16;
  const int crow0 = (tid & 1) * 4;             // consumer LDS rows crow0..+3
  const int ccol  = (tid >> 1) * 2;            // consumer cols {ccol, ccol+1}

  for (int t = 0; t < T_; ++t) {
    const unsigned seq = (unsigned)(t + 1);

    // ---- stage1: 3 mats x 2 cols over K=256 (h in regs) ----
    f32x4 hv[8];
#pragma unroll
    for (int kt = 0; kt < 8; ++kt)
      hv[kt] = *(const f32x4*)(h_lds + mb * HPAD + kt * 32 + ks * 4);

    float acc[6] = {0.f, 0.f, 0.f, 0.f, 0.f, 0.f};
#pragma unroll
    for (int kt = 0; kt < 8; ++kt) {
      f32x4 h4 = hv[kt];
#pragma unroll
      for (int m = 0; m < 3; ++m)
#pragma unroll
        for (int cc = 0; cc < 2; ++cc) {
          f32x4 w4 = *(const f32x4*)(w1t + (m * NS + wave * 2 + cc) * 256 + kt * 32 + ks * 4);
          float s = acc[m * 2 + cc];
          s = fmaf(h4[0], w4[0], s); s = fmaf(h4[1], w4[1], s);
          s = fmaf(h4[2], w4[2], s); s = fmaf(h4[3], w4[3], s);
          acc[m * 2 + cc] = s;
        }
    }
#pragma unroll
    for (int i = 0; i < 6; ++i) {
      float v = acc[i];
      v += __shfl_xor(v, 1); v += __shfl_xor(v, 2); v += __shfl_xor(v, 4);
      acc[i] = v;
    }
    // ---- epilogue1 + immediate per-wave publish (8 ks==0 lanes, 128B) ----
    if (ks == 0) {
      f32x4 xi = *(const f32x4*)(xin + ((t & 1) * MB + mb) * 4);
      float a0  = ftanh(acc[0] + xi[0] * w1r0_[0] + b1_[0]);
      float a1  = ftanh(acc[1] + xi[0] * w1r0_[1] + b1_[1]);
      float p10 = ftanh(acc[2] + xi[1] * w1r0_[2] + b1_[2]);
      float p11 = ftanh(acc[3] + xi[1] * w1r0_[3] + b1_[3]);
      float p20 = ftanh(acc[4] + xi[2] * w1r0_[4] + b1_[4]);
      float p21 = ftanh(acc[5] + xi[2] * w1r0_[5] + b1_[5]);
      u32x4 ch;
      ch.x = __float_as_uint(a0 * p10 * p20 * (1.f - a0) * (1.f - p10) * (1.f - p20));
      ch.y = __float_as_uint(a1 * p11 * p21 * (1.f - a1) * (1.f - p11) * (1.f - p21));
      ch.z = seq; ch.w = 0u;
      sys_st_x4(u_my + mb * 4, ch);
    }

    // ---- u-hop cover window: x prefetch, out-GEMV, S2 h-part ----
    if (t + 1 < T_ && tid < MB) {
      float2 xt = *(const float2*)(x + ((b0 + tid) * T_ + (t + 1)) * 2);
      f32x4 xi; xi[0] = xt.x; xi[1] = cosf(xt.y); xi[2] = sinf(xt.y); xi[3] = 0.f;
      *(f32x4*)(xin + (((t + 1) & 1) * MB + tid) * 4) = xi;
    }
    if (t > 0 && ((t - 1) & (GC - 1)) == gc) {   // out[t-1] = h(t) @ Wo + bo
      int bb = wave * 2 + (lane >> 5);           // 2 batches per wave
      int kk = (lane & 31) * 8;
      const float* hr = h_lds + bb * HPAD + kk;
      f32x4 h4a = *(const f32x4*)(hr);
      f32x4 h4b = *(const f32x4*)(hr + 4);
      float v0 = 0.f, v1 = 0.f;
#pragma unroll
      for (int j = 0; j < 4; ++j) {
        v0 = fmaf(h4a[j], wo_s[(kk + j) * 2 + 0], v0);
        v1 = fmaf(h4a[j], wo_s[(kk + j) * 2 + 1], v1);
        v0 = fmaf(h4b[j], wo_s[(kk + 4 + j) * 2 + 0], v0);
        v1 = fmaf(h4b[j], wo_s[(kk + 4 + j) * 2 + 1], v1);
      }
      v0 += __shfl_xor(v0, 1);  v1 += __shfl_xor(v1, 1);
      v0 += __shfl_xor(v0, 2);  v1 += __shfl_xor(v1, 2);
      v0 += __shfl_xor(v0, 4);  v1 += __shfl_xor(v1, 4);
      v0 += __shfl_xor(v0, 8);  v1 += __shfl_xor(v1, 8);
      v0 += __shfl_xor(v0, 16); v1 += __shfl_xor(v1, 16);
      if ((lane & 31) == 0) {
        float2 o; o.x = v0 + bo0; o.y = v1 + bo1;
        *(float2*)(out + ((b0 + bb) * T_ + (t - 1)) * 2) = o;
      }
    }
    float acc2[4] = {0.f, 0.f, 0.f, 0.f};
#pragma unroll
    for (int kt = 0; kt < 8; ++kt) {
      f32x4 h4 = hv[kt];
#pragma unroll
      for (int m = 0; m < 2; ++m)
#pragma unroll
        for (int cc = 0; cc < 2; ++cc) {
          f32x4 w4 = *(const f32x4*)(w2t + (m * NS + wave * 2 + cc) * 512 + 256 + kt * 32 + ks * 4);
          float s = acc2[m * 2 + cc];
          s = fmaf(h4[0], w4[0], s); s = fmaf(h4[1], w4[1], s);
          s = fmaf(h4[2], w4[2], s); s = fmaf(h4[3], w4[3], s);
          acc2[m * 2 + cc] = s;
        }
    }

    // ---- consume u: poll own 4 chunks (64B), write 4 float2 to LDS ----
    {
      u32x4 A, Bq, Cq, Dq;
      for (;;) {
        sys_ld_quad(pu, A, Bq, Cq, Dq);
        if (A.z == seq && Bq.z == seq && Cq.z == seq && Dq.z == seq) break;
        __builtin_amdgcn_s_sleep(1);
      }
      float2 d;
      d.x = __uint_as_float(A.x);  d.y = __uint_as_float(A.y);
      *(float2*)(u_lds + (crow0 + 0) * HPAD + ccol) = d;
      d.x = __uint_as_float(Bq.x); d.y = __uint_as_float(Bq.y);
      *(float2*)(u_lds + (crow0 + 1) * HPAD + ccol) = d;
      d.x = __uint_as_float(Cq.x); d.y = __uint_as_float(Cq.y);
      *(float2*)(u_lds + (crow0 + 2) * HPAD + ccol) = d;
      d.x = __uint_as_float(Dq.x); d.y = __uint_as_float(Dq.y);
      *(float2*)(u_lds + (crow0 + 3) * HPAD + ccol) = d;
    }
    __syncthreads();                         // u_lds ready

    // ---- stage2 u-part ----
#pragma unroll
    for (int kt = 0; kt < 8; ++kt) {
      f32x4 u4 = *(const f32x4*)(u_lds + mb * HPAD + kt * 32 + ks * 4);
#pragma unroll
      for (int m = 0; m < 2; ++m)
#pragma unroll
        for (int cc = 0; cc < 2; ++cc) {
          f32x4 w4 = *(const f32x4*)(w2t + (m * NS + wave * 2 + cc) * 512 + kt * 32 + ks * 4);
          float s = acc2[m * 2 + cc];
          s = fmaf(u4[0], w4[0], s); s = fmaf(u4[1], w4[1], s);
          s = fmaf(u4[2], w4[2], s); s = fmaf(u4[3], w4[3], s);
          acc2[m * 2 + cc] = s;
        }
    }
#pragma unroll
    for (int i = 0; i < 4; ++i) {
      float v = acc2[i];
      v += __shfl_xor(v, 1); v += __shfl_xor(v, 2); v += __shfl_xor(v, 4);
      acc2[i] = v;
    }
    // ---- epilogue2 + per-wave publish h_new ----
    if (ks == 0) {
      float z0  = fsigm(acc2[0] + bz_[0]);
      float z1  = fsigm(acc2[1] + bz_[1]);
      float hc0 = ftanh(acc2[2] + bh_[0]);
      float hc1 = ftanh(acc2[3] + bh_[1]);
      float2 hp = *(const float2*)(h_lds + mb * HPAD + n0);
      float hn0 = z0 * hp.x + (1.f - z0) * hc0;
      float hn1 = z1 * hp.y + (1.f - z1) * hc1;
      u32x4 ch;
      ch.x = __float_as_uint(hn0); ch.y = __float_as_uint(hn1);
      ch.z = seq; ch.w = 0u;
      sys_st_x4(h_my + mb * 4, ch);
      if (t == T_ - 1) {
        float2 o; o.x = hn0; o.y = hn1;
        *(float2*)(out + B_ * T_ * 2 + (b0 + mb) * H_ + n0) = o;
      }
    }
    __syncthreads();   // h_lds readers (epi2, out-GEMV) done before overwrite

    // ---- consume h(t+1) -> h_lds ----
    {
      u32x4 A, Bq, Cq, Dq;
      for (;;) {
        sys_ld_quad(ph, A, Bq, Cq, Dq);
        if (A.z == seq && Bq.z == seq && Cq.z == seq && Dq.z == seq) break;
        __builtin_amdgcn_s_sleep(1);
      }
      float2 d;
      d.x = __uint_as_float(A.x);  d.y = __uint_as_float(A.y);
      *(float2*)(h_lds + (crow0 + 0) * HPAD + ccol) = d;
      d.x = __uint_as_float(Bq.x); d.y = __uint_as_float(Bq.y);
      *(float2*)(h_lds + (crow0 + 1) * HPAD + ccol) = d;
      d.x = __uint_as_float(Cq.x); d.y = __uint_as_float(Cq.y);
      *(float2*)(h_lds + (crow0 + 2) * HPAD + ccol) = d;
      d.x = __uint_as_float(Dq.x); d.y = __uint_as_float(Dq.y);
      *(float2*)(h_lds + (crow0 + 3) * HPAD + ccol) = d;
    }
    __syncthreads();                         // h(t+1) ready
  }

  // ---- tail: out[T-1] from h(T) (in h_lds) ----
  if (gc == ((T_ - 1) & (GC - 1))) {
    int bb = wave * 2 + (lane >> 5);
    int kk = (lane & 31) * 8;
    const float* hr = h_lds + bb * HPAD + kk;
    f32x4 h4a = *(const f32x4*)(hr);
    f32x4 h4b = *(const f32x4*)(hr + 4);
    float v0 = 0.f, v1 = 0.f;
#pragma unroll
    for (int j = 0; j < 4; ++j) {
      v0 = fmaf(h4a[j], wo_s[(kk + j) * 2 + 0], v0);
      v1 = fmaf(h4a[j], wo_s[(kk + j) * 2 + 1], v1);
      v0 = fmaf(h4b[j], wo_s[(kk + 4 + j) * 2 + 0], v0);
      v1 = fmaf(h4b[j], wo_s[(kk + 4 + j) * 2 + 1], v1);
    }
    v0 += __shfl_xor(v0, 1);  v1 += __shfl_xor(v1, 1);
    v0 += __shfl_xor(v0, 2);  v1 += __shfl_xor(v1, 2);
    v0 += __shfl_xor(v0, 4);  v1 += __shfl_xor(v1, 4);
    v0 += __shfl_xor(v0, 8);  v1 += __shfl_xor(v1, 8);
    v0 += __shfl_xor(v0, 16); v1 += __shfl_xor(v1, 16);
    if ((lane & 31) == 0) {
      float2 o; o.x = v0 + bo0; o.y = v1 + bo1;
      *(float2*)(out + ((b0 + bb) * T_ + (T_ - 1)) * 2) = o;
    }
  }
}

extern "C" void kernel_launch(void* const* d_in, const int* in_sizes, int n_in,
                              void* d_out, int out_size, void* d_ws, size_t ws_size,
                              hipStream_t stream) {
  (void)in_sizes; (void)n_in; (void)out_size; (void)ws_size;
  const float* x   = (const float*)d_in[0];
  const float* h0  = (const float*)d_in[1];
  const float* Wa  = (const float*)d_in[2];
  const float* ba  = (const float*)d_in[3];
  const float* Wp1 = (const float*)d_in[4];
  const float* bp1 = (const float*)d_in[5];
  const float* Wp2 = (const float*)d_in[6];
  const float* bp2 = (const float*)d_in[7];
  const float* Wz  = (const float*)d_in[8];
  const float* bz  = (const float*)d_in[9];
  const float* Wh  = (const float*)d_in[10];
  const float* bh  = (const float*)d_in[11];
  const float* Wo  = (const float*)d_in[12];
  const float* bo  = (const float*)d_in[13];

  float* out = (float*)d_out;
  char*  ws  = (char*)d_ws;
  unsigned* u_ex = (unsigned*)ws;                 // 16 groups * 16KB = 256 KB
  unsigned* h_ex = (unsigned*)(ws + 262144);      // 256 KB

  // seqs restart at 1 every replay -> zero exchange regions each launch.
  hipMemsetAsync(ws, 0, 524288, stream);

  pgjanet_persist<<<dim3(GB * GC), dim3(NTHR), 0, stream>>>(
      x, h0, Wa, ba, Wp1, bp1, Wp2, bp2, Wz, bz, Wh, bh, Wo, bo,
      out, u_ex, h_ex);
}

// Round 9
// 6947.575 us; speedup vs baseline: 1.3597x; 1.3597x over previous
//
#include <hip/hip_runtime.h>
#include <math.h>

// PGJANET persistent kernel, round 9.
// 32 batch-groups (MB=4 batches) x 8 col-slice WGs (NS=32 cols), grid 256,
// 512 thr. r4's proven 2-hop protocol (self-validating {f0,f1,seq,0} 16B
// chunks via sc0 sc1, per-thread single-chunk polls) + ALL weights hoisted to
// VGPRs (48+64 fp32/thread, zero weight-LDS traffic) + lane-parallel precise
// (libm) epilogues. Covers: u-hop <- S2 h-part; h-hop <- out-GEMV + x-prefetch.

#define B_   128
#define T_   1024
#define H_   256
#define GB   32
#define GC   8
#define MB   4
#define NS   32
#define NTHR 512
#define HP   260   // LDS row stride (floats); 260%32==4 spreads batch rows

typedef float    f32x4 __attribute__((ext_vector_type(4)));
typedef unsigned u32x4 __attribute__((ext_vector_type(4)));

__device__ __forceinline__ void sys_st_x4(unsigned* p, u32x4 v) {
  asm volatile("global_store_dwordx4 %0, %1, off sc0 sc1" :: "v"(p), "v"(v) : "memory");
}
__device__ __forceinline__ u32x4 sys_ld_x4(const unsigned* p) {
  u32x4 v;
  asm volatile("global_load_dwordx4 %0, %1, off sc0 sc1\n\ts_waitcnt vmcnt(0)"
               : "=v"(v) : "v"(p) : "memory");
  return v;
}

__launch_bounds__(NTHR, 1)
__global__ void pgjanet_persist(
    const float* __restrict__ x,   const float* __restrict__ h0,
    const float* __restrict__ Wa,  const float* __restrict__ ba,
    const float* __restrict__ Wp1, const float* __restrict__ bp1,
    const float* __restrict__ Wp2, const float* __restrict__ bp2,
    const float* __restrict__ Wz,  const float* __restrict__ bz,
    const float* __restrict__ Wh,  const float* __restrict__ bh,
    const float* __restrict__ Wo,  const float* __restrict__ bo,
    float* __restrict__ out,        // [B*T*2] then h_n [B*H]
    unsigned* __restrict__ u_ex,    // [GB][512 chunks * 4 uints]
    unsigned* __restrict__ h_ex)    // [GB][512 chunks * 4 uints]
{
  __shared__ __align__(16) float h_lds[MB][HP];   // full h for group's batches
  __shared__ __align__(16) float u_lds[MB][HP];   // full u
  __shared__ __align__(16) float wo_s[H_ * 2];    // 2 KB
  __shared__ __align__(16) float xin[2][MB][4];   // {amp,cos,sin,0} dbuf

  const int wg   = blockIdx.x;
  const int g    = wg >> 3;
  const int gc   = wg & 7;
  const int tid  = threadIdx.x;
  const int col  = tid >> 4;      // 0..31 (own col within slice)
  const int kk   = tid & 15;      // 16-way k-split lane
  const int b0   = g * MB;
  const int colg = gc * NS + col; // global column

  // ---- one-time: hoist fp32 weights to VGPRs ----
  // S1: k = kk*4 + j*64 + c  (16 k-values/thread, interleaved chunks)
  f32x4 w1r[3][4]; float w1r0_[3], b1_[3];
#pragma unroll
  for (int m = 0; m < 3; ++m) {
    const float* W  = (m == 0) ? Wa : (m == 1 ? Wp1 : Wp2);
    const float* bb = (m == 0) ? ba : (m == 1 ? bp1 : bp2);
#pragma unroll
    for (int j = 0; j < 4; ++j) {
      f32x4 w;
#pragma unroll
      for (int c = 0; c < 4; ++c)
        w[c] = W[(1 + kk * 4 + j * 64 + c) * H_ + colg];
      w1r[m][j] = w;
    }
    w1r0_[m] = W[colg];
    b1_[m]   = bb[colg];
  }
  // S2: K=512=[u(0..255), h(256..511)]; j<4 -> u rows, j>=4 -> h rows
  f32x4 w2r[2][8];
#pragma unroll
  for (int m = 0; m < 2; ++m) {
    const float* W = (m == 0) ? Wz : Wh;
#pragma unroll
    for (int j = 0; j < 8; ++j) {
      int rb = (j < 4) ? (kk * 4 + j * 64) : (256 + kk * 4 + (j - 4) * 64);
      f32x4 w;
#pragma unroll
      for (int c = 0; c < 4; ++c)
        w[c] = W[(rb + c) * H_ + colg];
      w2r[m][j] = w;
    }
  }
  const float bz_c = bz[colg], bh_c = bh[colg];
  const float bo0 = bo[0], bo1 = bo[1];
  for (int i = tid; i < H_ * 2; i += NTHR) wo_s[i] = Wo[i];
  {
    int b = tid >> 7, c2 = (tid & 127) * 2;
    float2 hv = *(const float2*)(h0 + (size_t)(b0 + b) * H_ + c2);
    h_lds[b][c2] = hv.x; h_lds[b][c2 + 1] = hv.y;
  }
  if (tid < MB) {
    float2 xt = *(const float2*)(x + ((size_t)(b0 + tid) * T_) * 2);
    xin[0][tid][0] = xt.x; xin[0][tid][1] = cosf(xt.y);
    xin[0][tid][2] = sinf(xt.y); xin[0][tid][3] = 0.f;
  }
  __syncthreads();

  unsigned* u_exg = u_ex + g * 2048;    // 512 chunks * 4 uints
  unsigned* h_exg = h_ex + g * 2048;
  unsigned* u_my  = u_exg + (gc * 64 + (col >> 1) * 4) * 4;  // + eb*4 at store
  unsigned* h_my  = h_exg + (gc * 64 + (col >> 1) * 4) * 4;
  const unsigned* pu = u_exg + tid * 4;     // consumer: chunk tid
  const unsigned* ph = h_exg + tid * 4;
  const int cpg = ((tid >> 6) * 16 + ((tid >> 2) & 15)) * 2;  // consumer col
  const int cb  = tid & 3;                                    // consumer batch
  const int em  = kk >> 2, eb = kk & 3;                       // epilogue role

  for (int t = 0; t < T_; ++t) {
    const unsigned seq = (unsigned)(t + 1);
    const int xb = t & 1;

    // ---- S1: 3 mats x own col over K=256 x 4 batches (weights in regs) ----
    float acc[12];
#pragma unroll
    for (int i = 0; i < 12; ++i) acc[i] = 0.f;
#pragma unroll
    for (int b = 0; b < MB; ++b) {
#pragma unroll
      for (int j = 0; j < 4; ++j) {
        f32x4 h4 = *(const f32x4*)&h_lds[b][kk * 4 + j * 64];
#pragma unroll
        for (int m = 0; m < 3; ++m) {
          float s = acc[m * 4 + b];
          s = fmaf(h4[0], w1r[m][j][0], s); s = fmaf(h4[1], w1r[m][j][1], s);
          s = fmaf(h4[2], w1r[m][j][2], s); s = fmaf(h4[3], w1r[m][j][3], s);
          acc[m * 4 + b] = s;
        }
      }
    }
#pragma unroll
    for (int i = 0; i < 12; ++i) {
      float v = acc[i];
      v += __shfl_xor(v, 1); v += __shfl_xor(v, 2);
      v += __shfl_xor(v, 4); v += __shfl_xor(v, 8);
      acc[i] = v;
    }
    // ---- S1 epilogue, lane-parallel: lane kk<12 handles (mat em, batch eb) ----
    {
      float pre1 = acc[0];
#pragma unroll
      for (int i = 1; i < 12; ++i) if (kk == i) pre1 = acc[i];
      float w0  = em == 0 ? w1r0_[0] : (em == 1 ? w1r0_[1] : w1r0_[2]);
      float bb1 = em == 0 ? b1_[0]   : (em == 1 ? b1_[1]   : b1_[2]);
      f32x4 xi4 = *(const f32x4*)&xin[xb][eb][0];
      float xim = em == 0 ? xi4[0] : (em == 1 ? xi4[1] : xi4[2]);
      float tv  = tanhf(pre1 + xim * w0 + bb1);      // a / p1 / p2 per role
      float p1v = __shfl(tv, kk + 4, 16);
      float p2v = __shfl(tv, kk + 8, 16);
      float uv  = tv * p1v * p2v * (1.f - tv) * (1.f - p1v) * (1.f - p2v);
      float uodd = __shfl_xor(uv, 16);               // partner col (col^1)
      if (kk < 4 && !(col & 1)) {
        u32x4 ch;
        ch.x = __float_as_uint(uv); ch.y = __float_as_uint(uodd);
        ch.z = seq; ch.w = 0u;
        sys_st_x4(u_my + eb * 4, ch);
      }
    }

    // ---- u-hop cover: S2 h-part (h in LDS, weights in regs) ----
    float acc2[8];
#pragma unroll
    for (int i = 0; i < 8; ++i) acc2[i] = 0.f;
#pragma unroll
    for (int b = 0; b < MB; ++b) {
#pragma unroll
      for (int j = 0; j < 4; ++j) {
        f32x4 h4 = *(const f32x4*)&h_lds[b][kk * 4 + j * 64];
#pragma unroll
        for (int m = 0; m < 2; ++m) {
          float s = acc2[m * 4 + b];
          s = fmaf(h4[0], w2r[m][4 + j][0], s); s = fmaf(h4[1], w2r[m][4 + j][1], s);
          s = fmaf(h4[2], w2r[m][4 + j][2], s); s = fmaf(h4[3], w2r[m][4 + j][3], s);
          acc2[m * 4 + b] = s;
        }
      }
    }

    // ---- poll + consume u (1 chunk/thread) ----
    {
      u32x4 c;
      for (;;) {
        c = sys_ld_x4(pu);
        if (c.z == seq) break;
        __builtin_amdgcn_s_sleep(1);
      }
      float2 d; d.x = __uint_as_float(c.x); d.y = __uint_as_float(c.y);
      *(float2*)&u_lds[cb][cpg] = d;
    }
    __syncthreads();                                 // B1: u_lds ready

    // ---- S2 u-part + reduce ----
#pragma unroll
    for (int b = 0; b < MB; ++b) {
#pragma unroll
      for (int j = 0; j < 4; ++j) {
        f32x4 u4 = *(const f32x4*)&u_lds[b][kk * 4 + j * 64];
#pragma unroll
        for (int m = 0; m < 2; ++m) {
          float s = acc2[m * 4 + b];
          s = fmaf(u4[0], w2r[m][j][0], s); s = fmaf(u4[1], w2r[m][j][1], s);
          s = fmaf(u4[2], w2r[m][j][2], s); s = fmaf(u4[3], w2r[m][j][3], s);
          acc2[m * 4 + b] = s;
        }
      }
    }
#pragma unroll
    for (int i = 0; i < 8; ++i) {
      float v = acc2[i];
      v += __shfl_xor(v, 1); v += __shfl_xor(v, 2);
      v += __shfl_xor(v, 4); v += __shfl_xor(v, 8);
      acc2[i] = v;
    }
    // ---- S2 epilogue, lane-parallel: kk<8 -> (em: 0=z 1=hc, batch eb) ----
    {
      float pre2 = acc2[0];
#pragma unroll
      for (int i = 1; i < 8; ++i) if (kk == i) pre2 = acc2[i];
      float v2 = pre2 + (em == 0 ? bz_c : bh_c);
      float gv;
      if (em == 0) gv = 1.f / (1.f + expf(-v2));     // z
      else         gv = tanhf(v2);                   // h_cand
      float hcv   = __shfl(gv, kk + 4, 16);
      float hprev = h_lds[eb][colg];
      float hn    = gv * hprev + (1.f - gv) * hcv;   // valid on kk<4
      float hnodd = __shfl_xor(hn, 16);
      if (kk < 4 && !(col & 1)) {
        u32x4 ch;
        ch.x = __float_as_uint(hn); ch.y = __float_as_uint(hnodd);
        ch.z = seq; ch.w = 0u;
        sys_st_x4(h_my + eb * 4, ch);
      }
      if (t == T_ - 1 && kk < 4)
        out[(size_t)B_ * T_ * 2 + (size_t)(b0 + eb) * H_ + colg] = hn;  // h_n
    }

    // ---- h-hop covers: out-GEMV (batch gc, wave0) + x prefetch ----
    if (t > 0 && gc < MB && tid < 64) {
      f32x4 h4  = *(const f32x4*)&h_lds[gc][tid * 4];
      f32x4 wo0 = *(const f32x4*)&wo_s[tid * 8];
      f32x4 wo1 = *(const f32x4*)&wo_s[tid * 8 + 4];
      float v0 = h4[0] * wo0[0] + h4[1] * wo0[2] + h4[2] * wo1[0] + h4[3] * wo1[2];
      float v1 = h4[0] * wo0[1] + h4[1] * wo0[3] + h4[2] * wo1[1] + h4[3] * wo1[3];
      v0 += __shfl_xor(v0, 1);  v1 += __shfl_xor(v1, 1);
      v0 += __shfl_xor(v0, 2);  v1 += __shfl_xor(v1, 2);
      v0 += __shfl_xor(v0, 4);  v1 += __shfl_xor(v1, 4);
      v0 += __shfl_xor(v0, 8);  v1 += __shfl_xor(v1, 8);
      v0 += __shfl_xor(v0, 16); v1 += __shfl_xor(v1, 16);
      v0 += __shfl_xor(v0, 32); v1 += __shfl_xor(v1, 32);
      if (tid == 0) {
        float2 o; o.x = v0 + bo0; o.y = v1 + bo1;
        *(float2*)(out + ((size_t)(b0 + gc) * T_ + (t - 1)) * 2) = o;
      }
    }
    if (t + 1 < T_ && tid < MB) {
      float2 xt = *(const float2*)(x + ((size_t)(b0 + tid) * T_ + (t + 1)) * 2);
      xin[xb ^ 1][tid][0] = xt.x; xin[xb ^ 1][tid][1] = cosf(xt.y);
      xin[xb ^ 1][tid][2] = sinf(xt.y); xin[xb ^ 1][tid][3] = 0.f;
    }
    __syncthreads();                                 // B2: all h_lds reads done

    // ---- poll + consume h(t+1) ----
    {
      u32x4 c;
      for (;;) {
        c = sys_ld_x4(ph);
        if (c.z == seq) break;
        __builtin_amdgcn_s_sleep(1);
      }
      float2 d; d.x = __uint_as_float(c.x); d.y = __uint_as_float(c.y);
      *(float2*)&h_lds[cb][cpg] = d;
    }
    __syncthreads();                                 // B3: h(t+1) ready
  }

  // ---- tail: out[:, T-1] from h(T) ----
  if (gc < MB && tid < 64) {
    f32x4 h4  = *(const f32x4*)&h_lds[gc][tid * 4];
    f32x4 wo0 = *(const f32x4*)&wo_s[tid * 8];
    f32x4 wo1 = *(const f32x4*)&wo_s[tid * 8 + 4];
    float v0 = h4[0] * wo0[0] + h4[1] * wo0[2] + h4[2] * wo1[0] + h4[3] * wo1[2];
    float v1 = h4[0] * wo0[1] + h4[1] * wo0[3] + h4[2] * wo1[1] + h4[3] * wo1[3];
    v0 += __shfl_xor(v0, 1);  v1 += __shfl_xor(v1, 1);
    v0 += __shfl_xor(v0, 2);  v1 += __shfl_xor(v1, 2);
    v0 += __shfl_xor(v0, 4);  v1 += __shfl_xor(v1, 4);
    v0 += __shfl_xor(v0, 8);  v1 += __shfl_xor(v1, 8);
    v0 += __shfl_xor(v0, 16); v1 += __shfl_xor(v1, 16);
    v0 += __shfl_xor(v0, 32); v1 += __shfl_xor(v1, 32);
    if (tid == 0) {
      float2 o; o.x = v0 + bo0; o.y = v1 + bo1;
      *(float2*)(out + ((size_t)(b0 + gc) * T_ + (T_ - 1)) * 2) = o;
    }
  }
}

extern "C" void kernel_launch(void* const* d_in, const int* in_sizes, int n_in,
                              void* d_out, int out_size, void* d_ws, size_t ws_size,
                              hipStream_t stream) {
  (void)in_sizes; (void)n_in; (void)out_size; (void)ws_size;
  const float* x   = (const float*)d_in[0];
  const float* h0  = (const float*)d_in[1];
  const float* Wa  = (const float*)d_in[2];
  const float* ba  = (const float*)d_in[3];
  const float* Wp1 = (const float*)d_in[4];
  const float* bp1 = (const float*)d_in[5];
  const float* Wp2 = (const float*)d_in[6];
  const float* bp2 = (const float*)d_in[7];
  const float* Wz  = (const float*)d_in[8];
  const float* bz  = (const float*)d_in[9];
  const float* Wh  = (const float*)d_in[10];
  const float* bh  = (const float*)d_in[11];
  const float* Wo  = (const float*)d_in[12];
  const float* bo  = (const float*)d_in[13];

  float* out = (float*)d_out;
  char*  ws  = (char*)d_ws;
  unsigned* u_ex = (unsigned*)ws;                 // 32 groups * 8KB = 256 KB
  unsigned* h_ex = (unsigned*)(ws + 262144);      // 256 KB

  // seqs restart at 1 every replay -> stale chunks from a previous replay
  // would carry valid-looking seqs. Zero both exchange regions each launch.
  hipMemsetAsync(ws, 0, 524288, stream);

  pgjanet_persist<<<dim3(GB * GC), dim3(NTHR), 0, stream>>>(
      x, h0, Wa, ba, Wp1, bp1, Wp2, bp2, Wz, bz, Wh, bh, Wo, bo,
      out, u_ex, h_ex);
}